// Round 10
// baseline (21.531 us; speedup 1.0000x reference)
//
#include <hip/hip_runtime.h>

#define N_PAT 4096
#define NMOD  4
#define OFFPAIRS 16773120.0   // N*(N-1)

// ---------------------------------------------------------------------------
// K1: blocks 0..255 = cox (scheduled first to overlap prep):
//     el[q]=exp(h[q]) staged in LDS once; t hoisted to 16 float4 VGPRs
//     (row-invariant); 16 i's per block -> num_part[cb], den_part[cb].
//     Block 0 zeroes ctr (stream-ordered before K2).
// blocks 256..1279 = prep. Block pb covers 16 rows (modality m = pb>>8):
//     xn = x/max(||x||,eps); valid = !missing
//     -> part_v[pb][256] (sum valid*xn), part_D[pb] (sum valid*selfcos),
//        part_n[pb] (sum valid).
// ---------------------------------------------------------------------------
__global__ __launch_bounds__(256) void prep_cox_kernel(
    const float* __restrict__ eb, const float* __restrict__ h,
    const float* __restrict__ t, const int* __restrict__ ev,
    float* __restrict__ part_v, float* __restrict__ part_D,
    float* __restrict__ part_n, float* __restrict__ num_part,
    float* __restrict__ den_part, int* __restrict__ ctr)
{
  __shared__ float shmem[4096];             // cox: el ; prep: xsh (first 1 KB)
  __shared__ float dsh[4], nsh[4], rsh[8];
  int tid = threadIdx.x;
  int wid = tid >> 6, lane = tid & 63;
  int b = blockIdx.x;

  if (b < 256) {
    // ---- cox path ----
    if (b == 0 && tid == 0) *ctr = 0;
    float* el = shmem;
    for (int q = tid; q < N_PAT; q += 256) el[q] = expf(h[q]);
    // hoist t (row-invariant j-pattern) into registers
    float4 tv[16];
#pragma unroll
    for (int it = 0; it < 16; ++it)
      tv[it] = *(const float4*)(t + (it * 64 + lane) * 4);
    __syncthreads();

    float numw = 0.f, denw = 0.f;
#pragma unroll
    for (int r = 0; r < 4; ++r) {
      int i = b * 16 + wid * 4 + r;
      float ti = t[i];
      float s = 0.f;
#pragma unroll
      for (int it = 0; it < 16; ++it) {
        float4 evv = *(const float4*)(&el[(it * 64 + lane) * 4]);
        s += (tv[it].x >= ti) ? evv.x : 0.f;
        s += (tv[it].y >= ti) ? evv.y : 0.f;
        s += (tv[it].z >= ti) ? evv.z : 0.f;
        s += (tv[it].w >= ti) ? evv.w : 0.f;
      }
#pragma unroll
      for (int o = 32; o; o >>= 1) s += __shfl_xor(s, o, 64);
      if (lane == 0) {
        float e = (float)ev[i];
        numw += e * (h[i] - logf(s));
        denw += e;
      }
    }
    if (lane == 0) { rsh[wid] = numw; rsh[4 + wid] = denw; }
    __syncthreads();
    if (tid == 0) num_part[b] = (rsh[0] + rsh[1]) + (rsh[2] + rsh[3]);
    if (tid == 1) den_part[b] = (rsh[4] + rsh[5]) + (rsh[6] + rsh[7]);
  } else {
    // ---- prep path ----
    int pb = b - 256;                       // 0..1023
    float* xsh = shmem;                     // [4][256]
    float4 acc = {0.f, 0.f, 0.f, 0.f};
    float Dacc = 0.f, nacc = 0.f;
#pragma unroll
    for (int rr = 0; rr < 4; ++rr) {
      int row = pb * 16 + wid * 4 + rr;
      const float* base = eb + (size_t)row * 256;
      float4 v = *(const float4*)(base + lane * 4);
      float x0 = base[0];
      int eq = (v.x == x0) & (v.y == x0) & (v.z == x0) & (v.w == x0);
      float ss = v.x * v.x + v.y * v.y + v.z * v.z + v.w * v.w;
#pragma unroll
      for (int o = 32; o; o >>= 1) ss += __shfl_xor(ss, o, 64);
      int missing = __all(eq);
      float denom = fmaxf(sqrtf(ss), 1e-8f);
      float inv = missing ? 0.0f : (1.0f / denom);
      acc.x += v.x * inv; acc.y += v.y * inv;
      acc.z += v.z * inv; acc.w += v.w * inv;
      Dacc += missing ? 0.0f : (ss * inv * inv);   // self-cos = ss/denom^2
      nacc += missing ? 0.0f : 1.0f;
    }
    xsh[wid * 256 + lane * 4 + 0] = acc.x;
    xsh[wid * 256 + lane * 4 + 1] = acc.y;
    xsh[wid * 256 + lane * 4 + 2] = acc.z;
    xsh[wid * 256 + lane * 4 + 3] = acc.w;
    if (lane == 0) { dsh[wid] = Dacc; nsh[wid] = nacc; }
    __syncthreads();
    part_v[(size_t)pb * 256 + tid] =
        (xsh[tid] + xsh[256 + tid]) + (xsh[512 + tid] + xsh[768 + tid]);
    if (tid == 0) part_D[pb] = (dsh[0] + dsh[1]) + (dsh[2] + dsh[3]);
    if (tid == 1) part_n[pb] = (nsh[0] + nsh[1]) + (nsh[2] + nsh[3]);
  }
}

// ---------------------------------------------------------------------------
// K2: 64 blocks. Block g (m = g>>4, cq = g&15):
//   (1) v[m][d] for d in cq*16..+15: sum 256 part_v rows (16-row chunks per
//       thread, fixed-order LDS combine) -> vsq64[g] = sum_d v_d^2.
//   (2) D64[g], n64[g]: sum part_D/part_n[g*16..+15].
//   (3) num64[g], den64[g]: sum num_part/den_part[g*4..+3].
// Last block (agent-scope counter) computes out in FIXED order.
// ---------------------------------------------------------------------------
__global__ __launch_bounds__(256) void reduce_finalize_kernel(
    const float* __restrict__ part_v, const float* __restrict__ part_D,
    const float* __restrict__ part_n, const float* __restrict__ num_part,
    const float* __restrict__ den_part, const float* __restrict__ Mp,
    float* __restrict__ vsq64, float* __restrict__ D64,
    float* __restrict__ n64, float* __restrict__ num64,
    float* __restrict__ den64, int* __restrict__ ctr,
    float* __restrict__ out)
{
  __shared__ float vsh[16][16];
  __shared__ int lastflag;
  int tid = threadIdx.x;
  int g = blockIdx.x;
  int m = g >> 4, cq = g & 15;
  int rc = tid >> 4, c = tid & 15;

  // (1) each thread: 16 rows at column d
  {
    const float* vb = part_v + ((size_t)(m * 256 + rc * 16)) * 256 + cq * 16 + c;
    float s = 0.f;
#pragma unroll
    for (int k = 0; k < 16; ++k) s += vb[k * 256];
    vsh[rc][c] = s;
  }
  __syncthreads();

  if (tid < 16) {
    float vd = 0.f;
#pragma unroll
    for (int k = 0; k < 16; ++k) vd += vsh[k][tid];   // fixed order
    float vsq = vd * vd;
    float Dv = part_D[g * 16 + tid];
    float nv = part_n[g * 16 + tid];
    float nm = (tid < 4) ? num_part[g * 4 + tid] : 0.f;
    float dn = (tid < 4) ? den_part[g * 4 + tid] : 0.f;
#pragma unroll
    for (int o = 8; o; o >>= 1) {
      vsq += __shfl_xor(vsq, o, 64);
      Dv  += __shfl_xor(Dv, o, 64);
      nv  += __shfl_xor(nv, o, 64);
      nm  += __shfl_xor(nm, o, 64);
      dn  += __shfl_xor(dn, o, 64);
    }
    if (tid == 0) {
      vsq64[g] = vsq; D64[g] = Dv; n64[g] = nv; num64[g] = nm; den64[g] = dn;
    }
  }
  __syncthreads();
  if (tid == 0) {
    __threadfence();                        // publish partials
    int prev = __hip_atomic_fetch_add(ctr, 1, __ATOMIC_ACQ_REL,
                                      __HIP_MEMORY_SCOPE_AGENT);
    lastflag = (prev == 63);
  }
  __syncthreads();

  if (lastflag && tid == 0) {
    __threadfence();                        // acquire side
    double sim = (double)Mp[0] * OFFPAIRS;
    for (int mm = 0; mm < NMOD; ++mm) {
      double Dm = 0.0, nmm = 0.0;
      for (int q = 0; q < 16; ++q) {
        Dm  += (double)D64[mm * 16 + q];
        nmm += (double)n64[mm * 16 + q];
      }
      sim += nmm * Dm;
    }
    for (int q = 0; q < 64; ++q) sim -= (double)vsq64[q];
    double n = 0.0, dd = 0.0;
    for (int q = 0; q < 64; ++q) { n += (double)num64[q]; dd += (double)den64[q]; }
    out[0] = (float)(-n / dd + sim);
  }
}

// ---------------------------------------------------------------------------
extern "C" void kernel_launch(void* const* d_in, const int* in_sizes, int n_in,
                              void* d_out, int out_size, void* d_ws, size_t ws_size,
                              hipStream_t stream)
{
  const float* h  = (const float*)d_in[0];
  const float* eb = (const float*)d_in[1];
  const float* tm = (const float*)d_in[2];
  const int*   ev = (const int*)d_in[3];
  const float* Mp = (const float*)d_in[4];
  float* out = (float*)d_out;

  char* ws = (char*)d_ws;
  float* part_v   = (float*)ws;                 // 1 MB  (1024 x 256)
  float* part_D   = part_v + 1024 * 256;        // 4 KB
  float* part_n   = part_D + 1024;              // 4 KB
  float* num_part = part_n + 1024;              // 1 KB
  float* den_part = num_part + 256;             // 1 KB
  float* vsq64    = den_part + 256;             // 256 B
  float* D64      = vsq64 + 64;                 // 256 B
  float* n64      = D64 + 64;                   // 256 B
  float* num64    = n64 + 64;                   // 256 B
  float* den64    = num64 + 64;                 // 256 B
  int*   ctr      = (int*)(den64 + 64);

  prep_cox_kernel<<<dim3(1280), dim3(256), 0, stream>>>(
      eb, h, tm, ev, part_v, part_D, part_n, num_part, den_part, ctr);
  reduce_finalize_kernel<<<dim3(64), dim3(256), 0, stream>>>(
      part_v, part_D, part_n, num_part, den_part, Mp,
      vsq64, D64, n64, num64, den64, ctr, out);
}

// Round 11
// 19.002 us; speedup vs baseline: 1.1331x; 1.1331x over previous
//
#include <hip/hip_runtime.h>

#define N_PAT 4096
#define NMOD  4
#define OFFPAIRS 16773120.0   // N*(N-1)

// ---------------------------------------------------------------------------
// K1: blocks 0..1023 = prep. Block b covers 16 rows (one modality, m = b>>8;
//     wave w handles rows b*16 + w*4 .. +3, register-accumulated):
//       xn = x/max(||x||,eps); valid = !missing; acc += valid*xn
//       D += valid*ss/denom^2 ; n += valid
//     -> part_v[b][256], part_D[b], part_n[b].
// blocks 1024..1279 = cox: sumexp[i] = sum_j [t_j >= t_i]*exp(h_j),
//     16 i's per block, t/eh staged in LDS.
// ---------------------------------------------------------------------------
__global__ __launch_bounds__(256) void prep_cox_kernel(
    const float* __restrict__ eb, const float* __restrict__ h,
    const float* __restrict__ t,
    float* __restrict__ part_v, float* __restrict__ part_D,
    float* __restrict__ part_n, float* __restrict__ sumexp)
{
  __shared__ float shmem[8192];             // 32 KB, shared by both paths
  int tid = threadIdx.x;
  int wid = tid >> 6, lane = tid & 63;
  int b = blockIdx.x;

  if (b < 1024) {
    float* xsh = shmem;                     // [4][256] per-wave masked-xn sums
    float* dsh = shmem + 1024;              // [4] D partial
    float* nsh = shmem + 1028;              // [4] n partial
    float4 acc = {0.f, 0.f, 0.f, 0.f};
    float Dacc = 0.f, nacc = 0.f;
#pragma unroll
    for (int rr = 0; rr < 4; ++rr) {
      int row = b * 16 + wid * 4 + rr;
      const float* base = eb + (size_t)row * 256;
      float4 v = *(const float4*)(base + lane * 4);
      float x0 = base[0];
      int eq = (v.x == x0) & (v.y == x0) & (v.z == x0) & (v.w == x0);
      float ss = v.x * v.x + v.y * v.y + v.z * v.z + v.w * v.w;
#pragma unroll
      for (int o = 32; o; o >>= 1) ss += __shfl_xor(ss, o, 64);
      int missing = __all(eq);
      float denom = fmaxf(sqrtf(ss), 1e-8f);
      float inv = missing ? 0.0f : (1.0f / denom);
      acc.x += v.x * inv; acc.y += v.y * inv;
      acc.z += v.z * inv; acc.w += v.w * inv;
      Dacc += missing ? 0.0f : (ss * inv * inv);   // self-cos = ss/denom^2
      nacc += missing ? 0.0f : 1.0f;
    }
    xsh[wid * 256 + lane * 4 + 0] = acc.x;
    xsh[wid * 256 + lane * 4 + 1] = acc.y;
    xsh[wid * 256 + lane * 4 + 2] = acc.z;
    xsh[wid * 256 + lane * 4 + 3] = acc.w;
    if (lane == 0) { dsh[wid] = Dacc; nsh[wid] = nacc; }
    __syncthreads();
    part_v[(size_t)b * 256 + tid] =
        (xsh[tid] + xsh[256 + tid]) + (xsh[512 + tid] + xsh[768 + tid]);
    if (tid == 0) part_D[b] = (dsh[0] + dsh[1]) + (dsh[2] + dsh[3]);
    if (tid == 1) part_n[b] = (nsh[0] + nsh[1]) + (nsh[2] + nsh[3]);
  } else {
    // ---- cox path ----
    float* tl = shmem;
    float* el = shmem + 4096;
    for (int q = tid; q < N_PAT; q += 256) {
      tl[q] = t[q];
      el[q] = expf(h[q]);
    }
    __syncthreads();
    int cb = b - 1024;
#pragma unroll
    for (int r = 0; r < 4; ++r) {
      int i = cb * 16 + wid * 4 + r;
      float ti = tl[i];
      float s = 0.f;
#pragma unroll
      for (int it = 0; it < 16; ++it) {
        int j = (it * 64 + lane) * 4;
        float4 tv = *(const float4*)(&tl[j]);
        float4 ev = *(const float4*)(&el[j]);
        s += (tv.x >= ti) ? ev.x : 0.f;
        s += (tv.y >= ti) ? ev.y : 0.f;
        s += (tv.z >= ti) ? ev.z : 0.f;
        s += (tv.w >= ti) ? ev.w : 0.f;
      }
#pragma unroll
      for (int o = 32; o; o >>= 1) s += __shfl_xor(s, o, 64);
      if (lane == 0) sumexp[i] = s;
    }
  }
}

// ---------------------------------------------------------------------------
// K2: 16 blocks. Block g (m = g>>2, dq = g&3):
//   (1) v[m][d] for d in [dq*64, dq*64+64): sum 256 part_v rows; then
//       vsq_part[g] = sum_d v^2  (fixed-order).
//   (2) D_part[g], n_part[g]: sum part_D/part_n[g*64 .. g*64+63].
//   (3) cox slice: num_part[g], den_part[g] over i in [g*256,(g+1)*256).
// ---------------------------------------------------------------------------
__global__ __launch_bounds__(256) void reduce_kernel(
    const float* __restrict__ part_v, const float* __restrict__ part_D,
    const float* __restrict__ part_n, const float* __restrict__ h,
    const int* __restrict__ ev, const float* __restrict__ sumexp,
    float* __restrict__ vsq_part, float* __restrict__ D_part,
    float* __restrict__ n_part, float* __restrict__ num_part,
    float* __restrict__ den_part)
{
  __shared__ float vsh[4][64];
  __shared__ float rsh[2][4];
  int tid = threadIdx.x, lane = tid & 63, wid = tid >> 6;
  int g = blockIdx.x;
  int m = g >> 2, dq = g & 3;

  // (1) column sums of part_v slice
  int d = dq * 64 + lane;
  const float* vb = part_v + ((size_t)(m * 256 + wid * 64)) * 256 + d;
  float s = 0.f;
#pragma unroll 8
  for (int r = 0; r < 64; ++r) s += vb[(size_t)r * 256];
  vsh[wid][lane] = s;

  // (3) cox slice (one i per thread)
  int i = g * 256 + tid;
  float e = (float)ev[i];
  float num = e * (h[i] - logf(sumexp[i]));
  float den = e;
#pragma unroll
  for (int o = 32; o; o >>= 1) {
    num += __shfl_xor(num, o, 64);
    den += __shfl_xor(den, o, 64);
  }
  if (lane == 0) { rsh[0][wid] = num; rsh[1][wid] = den; }
  __syncthreads();

  if (wid == 0) {
    // finish (1): v_d then vsq over this block's 64 d's
    float vd = (vsh[0][lane] + vsh[1][lane]) + (vsh[2][lane] + vsh[3][lane]);
    float vsq = vd * vd;
#pragma unroll
    for (int o = 32; o; o >>= 1) vsq += __shfl_xor(vsq, o, 64);
    // (2): D/n slice
    float Dv = part_D[g * 64 + lane];
    float nv = part_n[g * 64 + lane];
#pragma unroll
    for (int o = 32; o; o >>= 1) {
      Dv += __shfl_xor(Dv, o, 64);
      nv += __shfl_xor(nv, o, 64);
    }
    if (lane == 0) {
      vsq_part[g] = vsq;
      D_part[g]   = Dv;
      n_part[g]   = nv;
      num_part[g] = rsh[0][0] + rsh[0][1] + rsh[0][2] + rsh[0][3];
      den_part[g] = rsh[1][0] + rsh[1][1] + rsh[1][2] + rsh[1][3];
    }
  }
}

// ---------------------------------------------------------------------------
// K3: final arithmetic from 80 partials (single wave).
//   sim = M*(N^2-N) + sum_m [ n_m*D_m ] - sum_g vsq_part[g]
//   out = -sum(num)/sum(den) + sim
// ---------------------------------------------------------------------------
__global__ __launch_bounds__(64) void finalize_kernel(
    const float* __restrict__ vsq_part, const float* __restrict__ D_part,
    const float* __restrict__ n_part, const float* __restrict__ num_part,
    const float* __restrict__ den_part, const float* __restrict__ Mp,
    float* __restrict__ out)
{
  if (threadIdx.x == 0) {
    double sim = (double)Mp[0] * OFFPAIRS;
    for (int m = 0; m < NMOD; ++m) {
      double Dm = 0.0, nm = 0.0;
      for (int q = 0; q < 4; ++q) {
        Dm += (double)D_part[m * 4 + q];
        nm += (double)n_part[m * 4 + q];
      }
      sim += nm * Dm;
    }
    for (int g = 0; g < 16; ++g) sim -= (double)vsq_part[g];
    double n = 0.0, d = 0.0;
    for (int g = 0; g < 16; ++g) { n += (double)num_part[g]; d += (double)den_part[g]; }
    out[0] = (float)(-n / d + sim);
  }
}

// ---------------------------------------------------------------------------
extern "C" void kernel_launch(void* const* d_in, const int* in_sizes, int n_in,
                              void* d_out, int out_size, void* d_ws, size_t ws_size,
                              hipStream_t stream)
{
  const float* h  = (const float*)d_in[0];
  const float* eb = (const float*)d_in[1];
  const float* tm = (const float*)d_in[2];
  const int*   ev = (const int*)d_in[3];
  const float* Mp = (const float*)d_in[4];
  float* out = (float*)d_out;

  char* ws = (char*)d_ws;
  float* part_v   = (float*)ws;                 // 1 MB  (1024 x 256)
  float* part_D   = part_v + 1024 * 256;        // 4 KB
  float* part_n   = part_D + 1024;              // 4 KB
  float* sumexp   = part_n + 1024;              // 16 KB
  float* vsq_part = sumexp + N_PAT;             // 16
  float* D_part   = vsq_part + 16;              // 16
  float* n_part   = D_part + 16;                // 16
  float* num_part = n_part + 16;                // 16
  float* den_part = num_part + 16;              // 16

  prep_cox_kernel<<<dim3(1280), dim3(256), 0, stream>>>(
      eb, h, tm, part_v, part_D, part_n, sumexp);
  reduce_kernel<<<dim3(16), dim3(256), 0, stream>>>(
      part_v, part_D, part_n, h, ev, sumexp,
      vsq_part, D_part, n_part, num_part, den_part);
  finalize_kernel<<<dim3(1), dim3(64), 0, stream>>>(
      vsq_part, D_part, n_part, num_part, den_part, Mp, out);
}